// Round 1
// baseline (766.740 us; speedup 1.0000x reference)
//
#include <hip/hip_runtime.h>

// BsplineEncoding: N=1M, D=3, K=64, cubic. Row = 195 fp32/point; 780 MB out.
//
// Ledger: R2/R3/R5 — three structurally different kernels (LDS-bulk stream,
// persistent dbuf, LDS param-table + register select) ALL pin at 270 us =
// 2.9 TB/s. Model that fits: cached stores WRITE-ALLOCATE on L2 miss ->
// 780 MB fetch + 780 MB write = 1.56 GB @ 5.8 TB/s = 270 us. The harness
// fillBufferAligned writes 3.12 GB at 6.27 TB/s with FETCH_SIZE ~= 0 — it
// streams with non-temporal stores.
//
// R6b = R5 + non-temporal output stores. __builtin_nontemporal_store needs a
// NATIVE vector type (clang ext_vector_type), not HIP's float4 class — that
// was R6's compile error. Nothing else changed.
//
// R7 = R6b resubmitted verbatim: previous round's bench died with an infra
// error (container failed twice) — no counters, no timing. Re-baselining.
// Prediction: FETCH_SIZE ~780 MB -> ~12 MB if NT stores bypass write-
// allocate; dur 270 -> ~130-150 us. If FETCH stays high, NT path is a no-op
// on this config and we attack the store path with inline-asm `nt` next.

typedef float vfloat4 __attribute__((ext_vector_type(4)));

constexpr int   DIMS        = 3;
constexpr int   K           = 64;
constexpr int   ROW         = DIMS * (1 + K);        // 195
constexpr float SCALE       = 30.5f;                 // (K-3)/2
constexpr float CLAMP_MAX   = 61.0f - 1e-6f;
constexpr int   PTS_PER_BLK = 64;
constexpr int   PAIRS       = PTS_PER_BLK * DIMS;    // 192 (point,dim) pairs
constexpr int   FLT_PER_BLK = PTS_PER_BLK * ROW;     // 12480
constexpr int   V4_PER_BLK  = FLT_PER_BLK / 4;       // 3120

__global__ __launch_bounds__(256)
void bspline_kernel(const float* __restrict__ x, float* __restrict__ out,
                    int n_pairs_total) {
    // 32-B records: [xv, idx_bits, c0, c1, c2, c3, pad, pad].
    __shared__ __align__(16) float params[(PAIRS + 1) * 8];
    const int t = threadIdx.x;

    // ---- Phase 1: one parameter eval per (point,dim) ----
    if (t < PAIRS) {
        const int gp = blockIdx.x * PAIRS + t;       // global pair = n*3+d
        float xv = 0.0f;
        if (gp < n_pairs_total) xv = x[gp];          // coalesced
        float xs = (xv + 1.0f) * SCALE;
        xs = fminf(fmaxf(xs, 0.0f), CLAMP_MAX);
        const int   idx = (int)xs;                   // xs>=0: trunc==floor
        const float u   = xs - (float)idx;
        const float u2  = u * u;
        const float u3  = u2 * u;
        const float om  = 1.0f - u;
        float* rec = params + t * 8;
        rec[0] = xv;
        rec[1] = __int_as_float(idx);
        rec[2] = om * om * om * (1.0f / 6.0f);
        rec[3] = (3.0f * u3 - 6.0f * u2 + 4.0f) * (1.0f / 6.0f);
        rec[4] = (-3.0f * u3 + 3.0f * u2 + 3.0f * u + 1.0f) * (1.0f / 6.0f);
        rec[5] = u3 * (1.0f / 6.0f);
    }
    if (t == 255) {                                  // zero the sentinel record
        float* rec = params + PAIRS * 8;
#pragma unroll
        for (int i = 0; i < 8; ++i) rec[i] = 0.0f;
    }
    __syncthreads();

    // ---- Phase 2: coalesced NON-TEMPORAL register-sourced store stream ----
    const float4* p4 = reinterpret_cast<const float4*>(params);
    vfloat4* out4 = reinterpret_cast<vfloat4*>(out)
                  + (long long)blockIdx.x * V4_PER_BLK;

    for (int f = t; f < V4_PER_BLK; f += 256) {
        const int pos = f * 4;                       // float offset in block
        const int p   = pos / 65;                    // pair index (magic mul)
        const int j   = pos - p * 65;                // 0..64 within pair
        const int p2  = p + ((j >= 62) ? 1 : 0);     // crossing partner

        const float4 a0 = p4[p * 2];                 // xv, idx, c0, c1
        const float4 a1 = p4[p * 2 + 1];             // c2, c3, -, -
        const float4 b0 = p4[p2 * 2];
        const float4 b1 = p4[p2 * 2 + 1];
        const int ia = __float_as_int(a0.y);
        const int ib = __float_as_int(b0.y);

        vfloat4 comp;
#pragma unroll
        for (int c = 0; c < 4; ++c) {
            const int  o  = j + c;
            const bool cr = (o >= 65);
            const int  oo = cr ? (o - 65) : o;
            const float xv = cr ? b0.x : a0.x;
            const float k0 = cr ? b0.z : a0.z;
            const float k1 = cr ? b0.w : a0.w;
            const float k2 = cr ? b1.x : a1.x;
            const float k3 = cr ? b1.y : a1.y;
            const int  tt = oo - 1 - (cr ? ib : ia);
            float v = 0.0f;
            v = (tt == 0) ? k0 : v;
            v = (tt == 1) ? k1 : v;
            v = (tt == 2) ? k2 : v;
            v = (tt == 3) ? k3 : v;
            v = (oo == 0) ? xv : v;
            comp[c] = v;
        }
        __builtin_nontemporal_store(comp, &out4[f]);
    }
}

extern "C" void kernel_launch(void* const* d_in, const int* in_sizes, int n_in,
                              void* d_out, int out_size, void* d_ws, size_t ws_size,
                              hipStream_t stream) {
    const float* x  = (const float*)d_in[0];
    float* out      = (float*)d_out;
    const int n_pts = in_sizes[0] / DIMS;                         // 1,000,000
    const int nblk  = (n_pts + PTS_PER_BLK - 1) / PTS_PER_BLK;    // 15625
    bspline_kernel<<<dim3(nblk), dim3(256), 0, stream>>>(x, out, n_pts * DIMS);
}

// Round 2
// 763.722 us; speedup vs baseline: 1.0040x; 1.0040x over previous
//
#include <hip/hip_runtime.h>

// BsplineEncoding: N=1M, D=3, K=64, cubic. Row = 195 fp32/point; 780 MB out.
//
// Ledger:
//  R2/R3/R5 (prev session): three structures pinned ~270 us kernel-time
//    (2.9 TB/s). Ledger blamed L2 write-allocate (780 MB fetch + 780 MB wr).
//  R6b: + __builtin_nontemporal_store. R7 bench: dur_us 766.7 (= ~490 us
//    harness poison-fill + ~276 us kernel) — UNCHANGED vs plain stores.
//    Counter evidence: fills write 3.12 GB @ 6.32 TB/s with FETCH~=0, i.e.
//    full-line streams don't write-allocate on this chip. Our stores are
//    full-line too => write-allocate theory REJECTED.
//  R8 (this): new theory — store issue is gated by per-store LDS+VALU deps
//    (4x ds_read_b128 + ~60 VALU selects per 16-B store, serial lgkmcnt).
//    Restructure: materialize final rows in LDS (zero + 5-float scatter per
//    pair), then fill-shaped phase 2: batch 12x ds_read_b128 -> regs, then
//    12 back-to-back NT store_dwordx4. Predict kernel 276 -> ~130-170 us,
//    dur_us 766.7 -> ~620-660. If unchanged: store-path pin, try asm `nt`.

typedef float vfloat4 __attribute__((ext_vector_type(4)));

constexpr int   DIMS        = 3;
constexpr int   K           = 64;
constexpr int   ROW         = DIMS * (1 + K);          // 195
constexpr float SCALE       = 30.5f;                   // (K-3)/2
constexpr float CLAMP_MAX   = 61.0f - 1e-6f;
constexpr int   PTS_PER_BLK = 64;
constexpr int   PAIRS       = PTS_PER_BLK * DIMS;      // 192 (point,dim) pairs
constexpr int   FLT_PER_BLK = PTS_PER_BLK * ROW;       // 12480
constexpr int   V4_PER_BLK  = FLT_PER_BLK / 4;         // 3120
constexpr int   FULL_ITERS  = V4_PER_BLK / 256;        // 12
constexpr int   TAIL        = V4_PER_BLK - FULL_ITERS * 256;  // 48

__global__ __launch_bounds__(256)
void bspline_kernel(const float* __restrict__ x, float* __restrict__ out,
                    int n_pairs_total) {
    // Final output tile, exactly in output layout: pair p -> floats
    // [p*65 .. p*65+64] = [xv, feat[0..63]].
    __shared__ __align__(16) float tile[FLT_PER_BLK];  // 49.92 KB -> 3 blk/CU
    vfloat4* t4 = reinterpret_cast<vfloat4*>(tile);
    const int t = threadIdx.x;

    // ---- Phase 0: zero the tile (conflict-free b128 writes) ----
    const vfloat4 z = {0.0f, 0.0f, 0.0f, 0.0f};
#pragma unroll
    for (int i = 0; i < FULL_ITERS; ++i) t4[t + i * 256] = z;
    if (t < TAIL) t4[FULL_ITERS * 256 + t] = z;
    __syncthreads();

    // ---- Phase 1: one param eval per (point,dim); scatter 5 floats ----
    if (t < PAIRS) {
        const int gp = blockIdx.x * PAIRS + t;         // global pair = n*3+d
        float xv = 0.0f;
        if (gp < n_pairs_total) xv = x[gp];            // coalesced
        float xs = (xv + 1.0f) * SCALE;
        xs = fminf(fmaxf(xs, 0.0f), CLAMP_MAX);
        const int   idx = (int)xs;                     // xs>=0: trunc==floor
        const float u   = xs - (float)idx;
        const float u2  = u * u;
        const float u3  = u2 * u;
        const float om  = 1.0f - u;
        float* base = tile + t * 65;
        base[0]       = xv;
        base[1 + idx] = om * om * om * (1.0f / 6.0f);
        base[2 + idx] = (3.0f * u3 - 6.0f * u2 + 4.0f) * (1.0f / 6.0f);
        base[3 + idx] = (-3.0f * u3 + 3.0f * u2 + 3.0f * u + 1.0f) * (1.0f / 6.0f);
        base[4 + idx] = u3 * (1.0f / 6.0f);
    }
    __syncthreads();

    // ---- Phase 2: fill-shaped stream. 12 batched ds_read_b128 into regs,
    // then 12 back-to-back NT store_dwordx4 (no per-store LDS dependency) ----
    vfloat4* out4 = reinterpret_cast<vfloat4*>(out)
                  + (long long)blockIdx.x * V4_PER_BLK;
    vfloat4 v[FULL_ITERS];
#pragma unroll
    for (int i = 0; i < FULL_ITERS; ++i) v[i] = t4[t + i * 256];
#pragma unroll
    for (int i = 0; i < FULL_ITERS; ++i)
        __builtin_nontemporal_store(v[i], &out4[t + i * 256]);
    if (t < TAIL) {
        const vfloat4 vt = t4[FULL_ITERS * 256 + t];
        __builtin_nontemporal_store(vt, &out4[FULL_ITERS * 256 + t]);
    }
}

extern "C" void kernel_launch(void* const* d_in, const int* in_sizes, int n_in,
                              void* d_out, int out_size, void* d_ws, size_t ws_size,
                              hipStream_t stream) {
    const float* x  = (const float*)d_in[0];
    float* out      = (float*)d_out;
    const int n_pts = in_sizes[0] / DIMS;                         // 1,000,000
    const int nblk  = (n_pts + PTS_PER_BLK - 1) / PTS_PER_BLK;    // 15625
    bspline_kernel<<<dim3(nblk), dim3(256), 0, stream>>>(x, out, n_pts * DIMS);
}